// Round 7
// baseline (15.685 us; speedup 1.0000x reference)
//
#include <hip/hip_runtime.h>

// Separable 5x5 median (median of row-medians), zero-padded, f32.
// Thread = 4 consecutive columns (float4) x strip of TH=4 rows.
// Depth-2 row prefetch (load h+4 while consuming h+2: ~280 VALU cycles
// load->use) x 6 waves/SIMD => latency fully covered even for cold HBM.
// shfl horizontal halo; nontemporal stores (r3/r4 A/B: +2.4us).

#define CE(a, b) { float _t = fminf(a, b); (b) = fmaxf(a, b); (a) = _t; }

typedef float f32x4 __attribute__((ext_vector_type(4)));

__device__ __forceinline__ float med5(float a0, float a1, float a2, float a3, float a4) {
    CE(a0, a1); CE(a2, a3); CE(a0, a2); CE(a1, a3); CE(a1, a2);
    return fmaxf(a1, fminf(a4, a2));
}

struct Row { float4 C; float e0, e1; };

__global__ __launch_bounds__(256) void median5_kernel(const float* __restrict__ in,
                                                      float* __restrict__ out) {
    constexpr int W = 512, H = 512, TH = 4;
    int idx   = blockIdx.x * blockDim.x + threadIdx.x;
    int cg    = idx & 127;             // column group (4 cols each)
    int strip = (idx >> 7) & 127;      // H / TH = 128 strips
    int bc    = idx >> 14;             // plane 0..23

    const float* p = in  + (size_t)bc * H * W;
    float*       q = out + (size_t)bc * H * W;
    const int h0 = strip * TH;
    const int w4 = cg * 4;
    const int lane = threadIdx.x & 63;
    const bool lEdge = (lane == 0);
    const bool rEdge = (lane == 63);
    const float4 z4 = make_float4(0.f, 0.f, 0.f, 0.f);

    auto rawload = [&](int ih) -> Row {
        Row r;
        if (ih < 0 || ih >= H) { r.C = z4; r.e0 = 0.f; r.e1 = 0.f; return r; }
        const float* rp = p + ih * W;
        r.C = *(const float4*)(rp + w4);
        float a = 0.f, b = 0.f;
        if (lEdge && w4 >= 4)    { a = rp[w4 - 2]; b = rp[w4 - 1]; }
        if (rEdge && w4 + 4 < W) { a = rp[w4 + 4]; b = rp[w4 + 5]; }
        r.e0 = a; r.e1 = b;
        return r;
    };

    auto rowmed = [&](const Row& rr) -> float4 {
        float4 C = rr.C;
        float lz = __shfl_up(C.z, 1);
        float lw = __shfl_up(C.w, 1);
        float rx = __shfl_down(C.x, 1);
        float ry = __shfl_down(C.y, 1);
        if (lEdge) { lz = rr.e0; lw = rr.e1; }
        if (rEdge) { rx = rr.e0; ry = rr.e1; }
        float4 m;
        m.x = med5(lz, lw, C.x, C.y, C.z);
        m.y = med5(lw, C.x, C.y, C.z, C.w);
        m.z = med5(C.x, C.y, C.z, C.w, rx);
        m.w = med5(C.y, C.z, C.w, rx, ry);
        return m;
    };

    // Prologue: 6 raw loads issued back-to-back, then 4 row-medians.
    Row q0 = rawload(h0 - 2);
    Row q1 = rawload(h0 - 1);
    Row q2 = rawload(h0);
    Row q3 = rawload(h0 + 1);
    Row rA = rawload(h0 + 2);   // consumed at i=0
    Row rB = rawload(h0 + 3);   // consumed at i=1
    float4 m0 = rowmed(q0);
    float4 m1 = rowmed(q1);
    float4 m2 = rowmed(q2);
    float4 m3 = rowmed(q3);
    float4 cA = q2.C;           // center row h0
    float4 cB = q3.C;           // center row h0+1

    #pragma unroll
    for (int i = 0; i < TH; ++i) {
        int h = h0 + i;
        Row rC = (i + 2 < TH) ? rawload(h + 4) : rA;  // depth-2 prefetch
        float4 m4 = rowmed(rA);                       // row h+2, loaded 2 iters ago
        float4 cC = rA.C;                             // center row h+2
        f32x4 o;
        o.x = (med5(m0.x, m1.x, m2.x, m3.x, m4.x) - cA.x) + cA.x;
        o.y = (med5(m0.y, m1.y, m2.y, m3.y, m4.y) - cA.y) + cA.y;
        o.z = (med5(m0.z, m1.z, m2.z, m3.z, m4.z) - cA.z) + cA.z;
        o.w = (med5(m0.w, m1.w, m2.w, m3.w, m4.w) - cA.w) + cA.w;
        __builtin_nontemporal_store(o, (f32x4*)(q + h * W + w4));
        m0 = m1; m1 = m2; m2 = m3; m3 = m4;
        cA = cB; cB = cC;
        rA = rB; rB = rC;
    }
}

extern "C" void kernel_launch(void* const* d_in, const int* in_sizes, int n_in,
                              void* d_out, int out_size, void* d_ws, size_t ws_size,
                              hipStream_t stream) {
    const float* in = (const float*)d_in[0];   // [8,3,512,512] f32
    float* out = (float*)d_out;
    constexpr int W = 512, H = 512, TH = 4, BC = 24;
    int total_threads = BC * (H / TH) * (W / 4);   // 393216
    int block = 256;
    int grid = total_threads / block;              // 1536
    median5_kernel<<<grid, block, 0, stream>>>(in, out);
}

// Round 8
// 14.944 us; speedup vs baseline: 1.0496x; 1.0496x over previous
//
#include <hip/hip_runtime.h>

// Separable 5x5 median (median of row-medians), zero-padded, f32.
// BEST VARIANT (r6, 14.97us): thread = 4 consecutive columns (float4) x
// strip of TH=8 rows; raw rows prefetched one iteration ahead; shfl-based
// horizontal halo; nontemporal stores (r3/r4 A/B: +2.4us, keeps L2
// read-clean). At the floor: ~50 MB mandatory HBM traffic (~8us) +
// harness graph-replay overhead (~7us); TH=4/8, prefetch depth 1/2,
// occupancy 2x all move <0.8us.

#define CE(a, b) { float _t = fminf(a, b); (b) = fmaxf(a, b); (a) = _t; }

typedef float f32x4 __attribute__((ext_vector_type(4)));

__device__ __forceinline__ float med5(float a0, float a1, float a2, float a3, float a4) {
    CE(a0, a1); CE(a2, a3); CE(a0, a2); CE(a1, a3); CE(a1, a2);
    return fmaxf(a1, fminf(a4, a2));
}

struct Row { float4 C; float e0, e1; };

__global__ __launch_bounds__(256) void median5_kernel(const float* __restrict__ in,
                                                      float* __restrict__ out) {
    constexpr int W = 512, H = 512, TH = 8;
    int idx   = blockIdx.x * blockDim.x + threadIdx.x;
    int cg    = idx & 127;            // column group (4 cols each)
    int strip = (idx >> 7) & 63;      // H / TH = 64 strips
    int bc    = idx >> 13;            // plane 0..23

    const float* p = in  + (size_t)bc * H * W;
    float*       q = out + (size_t)bc * H * W;
    const int h0 = strip * TH;
    const int w4 = cg * 4;
    const int lane = threadIdx.x & 63;
    const bool lEdge = (lane == 0);
    const bool rEdge = (lane == 63);
    const float4 z4 = make_float4(0.f, 0.f, 0.f, 0.f);

    auto rawload = [&](int ih) -> Row {
        Row r;
        if (ih < 0 || ih >= H) { r.C = z4; r.e0 = 0.f; r.e1 = 0.f; return r; }
        const float* rp = p + ih * W;
        r.C = *(const float4*)(rp + w4);
        float a = 0.f, b = 0.f;
        if (lEdge && w4 >= 4)    { a = rp[w4 - 2]; b = rp[w4 - 1]; }
        if (rEdge && w4 + 4 < W) { a = rp[w4 + 4]; b = rp[w4 + 5]; }
        r.e0 = a; r.e1 = b;
        return r;
    };

    auto rowmed = [&](const Row& rr) -> float4 {
        float4 C = rr.C;
        float lz = __shfl_up(C.z, 1);
        float lw = __shfl_up(C.w, 1);
        float rx = __shfl_down(C.x, 1);
        float ry = __shfl_down(C.y, 1);
        if (lEdge) { lz = rr.e0; lw = rr.e1; }
        if (rEdge) { rx = rr.e0; ry = rr.e1; }
        float4 m;
        m.x = med5(lz, lw, C.x, C.y, C.z);
        m.y = med5(lw, C.x, C.y, C.z, C.w);
        m.z = med5(C.x, C.y, C.z, C.w, rx);
        m.w = med5(C.y, C.z, C.w, rx, ry);
        return m;
    };

    Row r0 = rawload(h0 - 2);
    Row r1 = rawload(h0 - 1);
    Row r2 = rawload(h0);
    Row r3 = rawload(h0 + 1);
    Row r4 = rawload(h0 + 2);
    float4 m0 = rowmed(r0);
    float4 m1 = rowmed(r1);
    float4 m2 = rowmed(r2);
    float4 m3 = rowmed(r3);

    #pragma unroll
    for (int i = 0; i < TH; ++i) {
        int h = h0 + i;
        Row rN = (i + 1 < TH) ? rawload(h + 3) : r4;  // prefetch next iter's row
        float4 m4 = rowmed(r4);                       // consumes last iter's load
        float4 cA = r2.C;                             // center row h (no reload)
        f32x4 o;
        o.x = (med5(m0.x, m1.x, m2.x, m3.x, m4.x) - cA.x) + cA.x;
        o.y = (med5(m0.y, m1.y, m2.y, m3.y, m4.y) - cA.y) + cA.y;
        o.z = (med5(m0.z, m1.z, m2.z, m3.z, m4.z) - cA.z) + cA.z;
        o.w = (med5(m0.w, m1.w, m2.w, m3.w, m4.w) - cA.w) + cA.w;
        __builtin_nontemporal_store(o, (f32x4*)(q + h * W + w4));
        m0 = m1; m1 = m2; m2 = m3; m3 = m4;
        r2 = r3; r3 = r4; r4 = rN;
    }
}

extern "C" void kernel_launch(void* const* d_in, const int* in_sizes, int n_in,
                              void* d_out, int out_size, void* d_ws, size_t ws_size,
                              hipStream_t stream) {
    const float* in = (const float*)d_in[0];   // [8,3,512,512] f32
    float* out = (float*)d_out;
    constexpr int W = 512, H = 512, TH = 8, BC = 24;
    int total_threads = BC * (H / TH) * (W / 4);   // 196608
    int block = 256;
    int grid = total_threads / block;              // 768
    median5_kernel<<<grid, block, 0, stream>>>(in, out);
}